// Round 1
// baseline (5465.878 us; speedup 1.0000x reference)
//
#include <hip/hip_runtime.h>
#include <hip/hip_bf16.h>
#include <hip/hip_cooperative_groups.h>

namespace cg = cooperative_groups;

#define LL 128
#define BB 128
#define AA 512
#define II 512
#define HH 1024
#define GG 4096   // 4*H
#define KK 1024   // I+A == H

typedef __attribute__((ext_vector_type(8))) short short8;
typedef __attribute__((ext_vector_type(4))) float f32x4;

static __device__ __forceinline__ unsigned short f2b(float x) {
    union { float f; unsigned u; } v; v.f = x;
    unsigned r = v.u + 0x7fffu + ((v.u >> 16) & 1u);
    return (unsigned short)(r >> 16);
}
static __device__ __forceinline__ float b2f(unsigned short b) {
    union { unsigned u; float f; } v; v.u = ((unsigned)b) << 16; return v.f;
}

typedef const __attribute__((address_space(1))) unsigned char ga_u8;
typedef __attribute__((address_space(3))) unsigned char ls_u8;
static __device__ __forceinline__ void gload_lds16(void* lds_base, const void* gsrc) {
    // LDS dest: wave-uniform base, HW adds lane*16. Global src: per-lane.
    __builtin_amdgcn_global_load_lds((ga_u8*)gsrc, (ls_u8*)lds_base, 16, 0, 0);
}

// ---------------- pack kernels ----------------
__global__ void build_x_kernel(const float* __restrict__ act, const float* __restrict__ inF,
                               unsigned short* __restrict__ xb) {
    int stride = gridDim.x * blockDim.x;
    for (int idx = blockIdx.x * blockDim.x + threadIdx.x; idx < LL * BB * KK; idx += stride) {
        int i  = idx & (KK - 1);
        int lb = idx >> 10;
        float v;
        if (i < II) v = inF[(lb & (BB - 1)) * II + i];
        else        v = act[(size_t)lb * AA + (i - II)];
        xb[idx] = f2b(v);
    }
}

__global__ void cast_kernel(const float* __restrict__ s, unsigned short* __restrict__ d, int n) {
    int stride = gridDim.x * blockDim.x;
    for (int i = blockIdx.x * blockDim.x + threadIdx.x; i < n; i += stride) d[i] = f2b(s[i]);
}

// ---------------- phase 1: gates_x = xb @ W_ih^T (bf16 out) ----------------
__launch_bounds__(256)
__global__ void gemm_x_kernel(const unsigned short* __restrict__ Ab,   // [16384][1024] bf16
                              const unsigned short* __restrict__ Bb,   // [4096][1024] bf16 (B^T layout)
                              unsigned short* __restrict__ Cb) {       // [16384][4096] bf16
    __shared__ __attribute__((aligned(16))) unsigned short As[128 * 32];
    __shared__ __attribute__((aligned(16))) unsigned short Bs[128 * 32];
    const int tid  = threadIdx.x;
    const int lane = tid & 63;
    const int wid  = tid >> 6;
    const int wr = wid >> 1, wc = wid & 1;
    const int m0 = blockIdx.x * 128, n0 = blockIdx.y * 128;
    const int lrow = lane & 15, lko = (lane >> 4) * 8;
    f32x4 acc[4][4] = {};

    for (int kt = 0; kt < KK / 32; ++kt) {
        const int k0 = kt * 32;
        // stage A and B tiles: 512 chunks of 16B each per tile
        #pragma unroll
        for (int t = 0; t < 2; ++t) {
            int q   = t * 256 + tid;
            int row = q >> 2;
            int co  = (q & 3) * 8;
            gload_lds16(&As[(t * 256 + wid * 64) * 8], &Ab[(size_t)(m0 + row) * KK + k0 + co]);
            gload_lds16(&Bs[(t * 256 + wid * 64) * 8], &Bb[(size_t)(n0 + row) * KK + k0 + co]);
        }
        __syncthreads();   // drains vmcnt, LDS ready
        short8 af[4], bf[4];
        #pragma unroll
        for (int mi = 0; mi < 4; ++mi)
            af[mi] = *(const short8*)&As[(wr * 64 + mi * 16 + lrow) * 32 + lko];
        #pragma unroll
        for (int ni = 0; ni < 4; ++ni)
            bf[ni] = *(const short8*)&Bs[(wc * 64 + ni * 16 + lrow) * 32 + lko];
        #pragma unroll
        for (int mi = 0; mi < 4; ++mi)
            #pragma unroll
            for (int ni = 0; ni < 4; ++ni)
                acc[mi][ni] = __builtin_amdgcn_mfma_f32_16x16x32_bf16(af[mi], bf[ni], acc[mi][ni], 0, 0, 0);
        __syncthreads();   // compute done before next stage overwrites
    }
    #pragma unroll
    for (int mi = 0; mi < 4; ++mi) {
        #pragma unroll
        for (int ni = 0; ni < 4; ++ni) {
            int col = n0 + wc * 64 + ni * 16 + lrow;
            #pragma unroll
            for (int r = 0; r < 4; ++r) {
                int row = m0 + wr * 64 + mi * 16 + (lane >> 4) * 4 + r;
                Cb[(size_t)row * GG + col] = f2b(acc[mi][ni][r]);
            }
        }
    }
}

// ---------------- phase 2: persistent cooperative LSTM recurrence ----------------
// 256 blocks; block owns h-dims [4*bid, 4*bid+4) -> 16 gate rows {t*H + j0 + d}.
// W_hh slice lives in LDS pre-packed in MFMA B-fragment order. h ping-pongs in global bf16.
__launch_bounds__(512)
__global__ void lstm_kernel(const unsigned short* __restrict__ gx,   // [L*B][4096] bf16
                            const float* __restrict__ Whh,           // [4096][1024] f32
                            const float* __restrict__ bih,
                            const float* __restrict__ bhh,
                            const float* __restrict__ c0,            // [B][H] f32
                            unsigned short* __restrict__ hb,         // [2][B][H] bf16
                            float* __restrict__ out) {               // hs | h_n | c_n
    __shared__ __attribute__((aligned(16))) unsigned short wlds[32 * 64 * 8]; // [kt][lane][8]
    __shared__ float gates_s[BB * 16];
    __shared__ float c_s[BB * 4];
    __shared__ float bias_s[16];

    const int tid  = threadIdx.x;
    const int lane = tid & 63;
    const int w    = tid >> 6;          // 8 waves
    const int j0   = blockIdx.x * 4;

    // pack W_hh slice into fragment order (once)
    {
        int n  = lane & 15;
        int g  = (n >> 2) * HH + j0 + (n & 3);
        int ko = (lane >> 4) * 8;
        for (int kt = w * 4; kt < w * 4 + 4; ++kt) {
            const float* src = &Whh[(size_t)g * HH + kt * 32 + ko];
            unsigned short* dst = &wlds[(kt * 64 + lane) * 8];
            #pragma unroll
            for (int j = 0; j < 8; ++j) dst[j] = f2b(src[j]);
        }
    }
    if (tid < 16) {
        int g = (tid >> 2) * HH + j0 + (tid & 3);
        bias_s[tid] = bih[g] + bhh[g];
    }
    {
        int b = tid >> 2, d = tid & 3;
        c_s[tid] = c0[b * HH + j0 + d];
    }
    __syncthreads();

    cg::grid_group grid = cg::this_grid();

    const int arow = w * 16 + (lane & 15);   // batch row this lane reads for A
    const int ako  = (lane >> 4) * 8;

    for (int l = 0; l < LL; ++l) {
        const unsigned short* hr = hb + (size_t)(l & 1) * (BB * HH);
        unsigned short*       hw = hb + (size_t)((l + 1) & 1) * (BB * HH);

        f32x4 acc0 = {0.f, 0.f, 0.f, 0.f}, acc1 = {0.f, 0.f, 0.f, 0.f};
        const unsigned short* hp = hr + (size_t)arow * HH + ako;
        #pragma unroll 8
        for (int kt = 0; kt < 32; kt += 2) {
            short8 a0 = *(const short8*)(hp + kt * 32);
            short8 b0 = *(const short8*)&wlds[(kt * 64 + lane) * 8];
            acc0 = __builtin_amdgcn_mfma_f32_16x16x32_bf16(a0, b0, acc0, 0, 0, 0);
            short8 a1 = *(const short8*)(hp + (kt + 1) * 32);
            short8 b1 = *(const short8*)&wlds[((kt + 1) * 64 + lane) * 8];
            acc1 = __builtin_amdgcn_mfma_f32_16x16x32_bf16(a1, b1, acc1, 0, 0, 0);
        }
        #pragma unroll
        for (int r = 0; r < 4; ++r)
            gates_s[(w * 16 + (lane >> 4) * 4 + r) * 16 + (lane & 15)] = acc0[r] + acc1[r];
        __syncthreads();

        {
            const int b = tid >> 2, d = tid & 3;
            const size_t gbase = ((size_t)l * BB + b) * GG + j0 + d;
            float gi = gates_s[b * 16 + 0  + d] + b2f(gx[gbase         ]) + bias_s[0  + d];
            float gf = gates_s[b * 16 + 4  + d] + b2f(gx[gbase + HH    ]) + bias_s[4  + d];
            float gg = gates_s[b * 16 + 8  + d] + b2f(gx[gbase + 2 * HH]) + bias_s[8  + d];
            float go = gates_s[b * 16 + 12 + d] + b2f(gx[gbase + 3 * HH]) + bias_s[12 + d];
            float ig = 1.f / (1.f + expf(-gi));
            float fg = 1.f / (1.f + expf(-gf));
            float og = 1.f / (1.f + expf(-go));
            float gt = tanhf(gg);
            float c1 = fg * c_s[tid] + ig * gt;
            float h1 = og * tanhf(c1);
            c_s[tid] = c1;
            hw[b * HH + j0 + d] = f2b(h1);
            out[(size_t)l * (BB * HH) + b * HH + j0 + d] = h1;
            if (l == LL - 1) {
                out[(size_t)LL * BB * HH + b * HH + j0 + d] = h1;
                out[(size_t)LL * BB * HH + BB * HH + b * HH + j0 + d] = c1;
            }
        }
        grid.sync();
    }
}

extern "C" void kernel_launch(void* const* d_in, const int* in_sizes, int n_in,
                              void* d_out, int out_size, void* d_ws, size_t ws_size,
                              hipStream_t stream) {
    const float* act = (const float*)d_in[0];
    const float* inF = (const float*)d_in[1];
    const float* h0  = (const float*)d_in[2];
    const float* c0  = (const float*)d_in[3];
    const float* Wih = (const float*)d_in[4];
    const float* Whh = (const float*)d_in[5];
    const float* bih = (const float*)d_in[6];
    const float* bhh = (const float*)d_in[7];
    float* out = (float*)d_out;

    char* p = (char*)d_ws;
    unsigned short* xb    = (unsigned short*)p; p += (size_t)LL * BB * KK * 2;   // 33.5 MB
    unsigned short* wih_b = (unsigned short*)p; p += (size_t)GG * KK * 2;        //  8.4 MB
    unsigned short* hb    = (unsigned short*)p; p += (size_t)2 * BB * HH * 2;    //  0.5 MB
    unsigned short* gx    = (unsigned short*)p; p += (size_t)LL * BB * GG * 2;   // 134 MB

    build_x_kernel<<<dim3(2048), dim3(256), 0, stream>>>(act, inF, xb);
    cast_kernel<<<dim3(1024), dim3(256), 0, stream>>>(Wih, wih_b, GG * KK);
    cast_kernel<<<dim3(64), dim3(256), 0, stream>>>(h0, hb, BB * HH);
    gemm_x_kernel<<<dim3(128, 32), dim3(256), 0, stream>>>(xb, wih_b, gx);

    void* args[] = { (void*)&gx, (void*)&Whh, (void*)&bih, (void*)&bhh,
                     (void*)&c0, (void*)&hb, (void*)&out };
    hipLaunchCooperativeKernel((const void*)lstm_kernel, dim3(256), dim3(512), args, 0, stream);
}

// Round 2
// 4858.635 us; speedup vs baseline: 1.1250x; 1.1250x over previous
//
#include <hip/hip_runtime.h>
#include <hip/hip_bf16.h>

#define LL 128
#define BB 128
#define AA 512
#define II 512
#define HH 1024
#define GG 4096   // 4*H
#define KK 1024   // I+A == H
#define NBLK 64   // blocks in recurrence kernel
#define DPB 16    // h-dims per block

typedef __attribute__((ext_vector_type(8))) short short8;
typedef __attribute__((ext_vector_type(4))) float f32x4;

static __device__ __forceinline__ unsigned short f2b(float x) {
    union { float f; unsigned u; } v; v.f = x;
    unsigned r = v.u + 0x7fffu + ((v.u >> 16) & 1u);
    return (unsigned short)(r >> 16);
}
static __device__ __forceinline__ float b2f(unsigned short b) {
    union { unsigned u; float f; } v; v.u = ((unsigned)b) << 16; return v.f;
}

typedef const __attribute__((address_space(1))) unsigned char ga_u8;
typedef __attribute__((address_space(3))) unsigned char ls_u8;
static __device__ __forceinline__ void gload_lds16(void* lds_base, const void* gsrc) {
    __builtin_amdgcn_global_load_lds((ga_u8*)gsrc, (ls_u8*)lds_base, 16, 0, 0);
}

// ---------------- pack kernels ----------------
__global__ void build_x_kernel(const float* __restrict__ act, const float* __restrict__ inF,
                               unsigned short* __restrict__ xb) {
    int stride = gridDim.x * blockDim.x;
    for (int idx = blockIdx.x * blockDim.x + threadIdx.x; idx < LL * BB * KK; idx += stride) {
        int i  = idx & (KK - 1);
        int lb = idx >> 10;
        float v;
        if (i < II) v = inF[(lb & (BB - 1)) * II + i];
        else        v = act[(size_t)lb * AA + (i - II)];
        xb[idx] = f2b(v);
    }
}

__global__ void cast_kernel(const float* __restrict__ s, unsigned short* __restrict__ d, int n) {
    int stride = gridDim.x * blockDim.x;
    for (int i = blockIdx.x * blockDim.x + threadIdx.x; i < n; i += stride) d[i] = f2b(s[i]);
}

// ---------------- phase 1: gates_x = xb @ W_ih^T (bf16 out) ----------------
__launch_bounds__(256)
__global__ void gemm_x_kernel(const unsigned short* __restrict__ Ab,   // [16384][1024] bf16
                              const unsigned short* __restrict__ Bb,   // [4096][1024] bf16 (B^T layout)
                              unsigned short* __restrict__ Cb) {       // [16384][4096] bf16
    __shared__ __attribute__((aligned(16))) unsigned short As[128 * 32];
    __shared__ __attribute__((aligned(16))) unsigned short Bs[128 * 32];
    const int tid  = threadIdx.x;
    const int lane = tid & 63;
    const int wid  = tid >> 6;
    const int wr = wid >> 1, wc = wid & 1;
    const int m0 = blockIdx.x * 128, n0 = blockIdx.y * 128;
    const int lrow = lane & 15, lko = (lane >> 4) * 8;
    f32x4 acc[4][4] = {};

    for (int kt = 0; kt < KK / 32; ++kt) {
        const int k0 = kt * 32;
        #pragma unroll
        for (int t = 0; t < 2; ++t) {
            int q   = t * 256 + tid;
            int row = q >> 2;
            int co  = (q & 3) * 8;
            gload_lds16(&As[(t * 256 + wid * 64) * 8], &Ab[(size_t)(m0 + row) * KK + k0 + co]);
            gload_lds16(&Bs[(t * 256 + wid * 64) * 8], &Bb[(size_t)(n0 + row) * KK + k0 + co]);
        }
        __syncthreads();
        short8 af[4], bf[4];
        #pragma unroll
        for (int mi = 0; mi < 4; ++mi)
            af[mi] = *(const short8*)&As[(wr * 64 + mi * 16 + lrow) * 32 + lko];
        #pragma unroll
        for (int ni = 0; ni < 4; ++ni)
            bf[ni] = *(const short8*)&Bs[(wc * 64 + ni * 16 + lrow) * 32 + lko];
        #pragma unroll
        for (int mi = 0; mi < 4; ++mi)
            #pragma unroll
            for (int ni = 0; ni < 4; ++ni)
                acc[mi][ni] = __builtin_amdgcn_mfma_f32_16x16x32_bf16(af[mi], bf[ni], acc[mi][ni], 0, 0, 0);
        __syncthreads();
    }
    #pragma unroll
    for (int mi = 0; mi < 4; ++mi) {
        #pragma unroll
        for (int ni = 0; ni < 4; ++ni) {
            int col = n0 + wc * 64 + ni * 16 + lrow;
            #pragma unroll
            for (int r = 0; r < 4; ++r) {
                int row = m0 + wr * 64 + mi * 16 + (lane >> 4) * 4 + r;
                Cb[(size_t)row * GG + col] = f2b(acc[mi][ni][r]);
            }
        }
    }
}

// ---------------- phase 2: persistent LSTM recurrence, custom barrier ----------------
// 64 blocks x 512 threads. Block owns h-dims [16*bid, 16*bid+16) => 64 gate rows,
// as 4 N-tiles (one per gate type). W_hh slice pre-packed in LDS in B-fragment
// order (128 KB). Wave w owns M-tile w (batches 16w..16w+15); all 4 gates
// accumulate in registers -> gate math + c-state fully register-resident.
__launch_bounds__(512)
__global__ void lstm_kernel(const unsigned short* __restrict__ gx,   // [L*B][4096] bf16
                            const float* __restrict__ Whh,           // [4096][1024] f32
                            const float* __restrict__ bih,
                            const float* __restrict__ bhh,
                            const float* __restrict__ c0,            // [B][H] f32
                            unsigned short* __restrict__ hb,         // [2][B][H] bf16
                            unsigned int* __restrict__ flags,        // [L] zeroed
                            float* __restrict__ out) {               // hs | h_n | c_n
    __shared__ __attribute__((aligned(16))) unsigned short wlds[4 * 32 * 64 * 8]; // 128 KB

    const int tid  = threadIdx.x;
    const int lane = tid & 63;
    const int w    = tid >> 6;          // 8 waves
    const int j0   = blockIdx.x * DPB;
    const int d    = lane & 15;         // dim within block / N index
    const int rgrp = lane >> 4;         // 0..3

    // pack W_hh slice into B-fragment order (once):
    // wlds[((t*32+kt)*64+lane)*8 + j] = bf16(Whh[(t*H + j0 + (lane&15))*H + kt*32 + (lane>>4)*8 + j])
    for (int idx = w; idx < 4 * 32; idx += 8) {
        int t = idx >> 5, kt = idx & 31;
        const float* src = &Whh[(size_t)(t * HH + j0 + d) * HH + kt * 32 + rgrp * 8];
        unsigned short* dst = &wlds[(idx * 64 + lane) * 8];
        #pragma unroll
        for (int j = 0; j < 8; ++j) dst[j] = f2b(src[j]);
    }
    float bias_r[4], c_r[4];
    #pragma unroll
    for (int t = 0; t < 4; ++t) bias_r[t] = bih[t * HH + j0 + d] + bhh[t * HH + j0 + d];
    const int b0 = w * 16 + rgrp * 4;   // first of this thread's 4 batches
    #pragma unroll
    for (int r = 0; r < 4; ++r) c_r[r] = c0[(b0 + r) * HH + j0 + d];
    __syncthreads();

    const int arow = w * 16 + d;        // batch row this lane loads for A
    const int ako  = rgrp * 8;

    for (int l = 0; l < LL; ++l) {
        const unsigned short* hr = hb + (size_t)(l & 1) * (BB * HH);
        unsigned short*       hw = hb + (size_t)((l + 1) & 1) * (BB * HH);

        // prefetch gx terms (hidden under MFMA loop)
        float gxv[4][4];
        #pragma unroll
        for (int r = 0; r < 4; ++r) {
            const unsigned short* gp = &gx[((size_t)l * BB + (b0 + r)) * GG + j0 + d];
            #pragma unroll
            for (int t = 0; t < 4; ++t) gxv[r][t] = b2f(gp[t * HH]);
        }

        f32x4 acc[4] = {};
        const unsigned short* hp = hr + (size_t)arow * HH + ako;
        #pragma unroll 4
        for (int kt = 0; kt < 32; ++kt) {
            short8 a = *(const short8*)(hp + kt * 32);
            #pragma unroll
            for (int t = 0; t < 4; ++t) {
                short8 bfr = *(const short8*)&wlds[((t * 32 + kt) * 64 + lane) * 8];
                acc[t] = __builtin_amdgcn_mfma_f32_16x16x32_bf16(a, bfr, acc[t], 0, 0, 0);
            }
        }

        #pragma unroll
        for (int r = 0; r < 4; ++r) {
            float gi = acc[0][r] + gxv[r][0] + bias_r[0];
            float gf = acc[1][r] + gxv[r][1] + bias_r[1];
            float gg = acc[2][r] + gxv[r][2] + bias_r[2];
            float go = acc[3][r] + gxv[r][3] + bias_r[3];
            float ig = 1.f / (1.f + __expf(-gi));
            float fg = 1.f / (1.f + __expf(-gf));
            float og = 1.f / (1.f + __expf(-go));
            float gt = tanhf(gg);
            float c1 = fg * c_r[r] + ig * gt;
            float h1 = og * tanhf(c1);
            c_r[r] = c1;
            hw[(b0 + r) * HH + j0 + d] = f2b(h1);
            out[((size_t)l * BB + (b0 + r)) * HH + j0 + d] = h1;
            if (l == LL - 1) {
                out[(size_t)LL * BB * HH + (b0 + r) * HH + j0 + d] = h1;
                out[(size_t)LL * BB * HH + BB * HH + (b0 + r) * HH + j0 + d] = c1;
            }
        }

        // --- lightweight grid barrier for step l ---
        __threadfence();                 // this thread's h/out stores device-visible
        __syncthreads();                 // whole block done writing
        if (tid == 0) {
            __hip_atomic_fetch_add(&flags[l], 1u, __ATOMIC_RELEASE, __HIP_MEMORY_SCOPE_AGENT);
            while (__hip_atomic_load(&flags[l], __ATOMIC_ACQUIRE, __HIP_MEMORY_SCOPE_AGENT) < NBLK) {}
        }
        __syncthreads();                 // all threads wait for tid0's acquire
        __threadfence();                 // invalidate stale lines before reading new h
    }
}

extern "C" void kernel_launch(void* const* d_in, const int* in_sizes, int n_in,
                              void* d_out, int out_size, void* d_ws, size_t ws_size,
                              hipStream_t stream) {
    const float* act = (const float*)d_in[0];
    const float* inF = (const float*)d_in[1];
    const float* h0  = (const float*)d_in[2];
    const float* c0  = (const float*)d_in[3];
    const float* Wih = (const float*)d_in[4];
    const float* Whh = (const float*)d_in[5];
    const float* bih = (const float*)d_in[6];
    const float* bhh = (const float*)d_in[7];
    float* out = (float*)d_out;

    char* p = (char*)d_ws;
    unsigned short* xb    = (unsigned short*)p; p += (size_t)LL * BB * KK * 2;   // 33.5 MB
    unsigned short* wih_b = (unsigned short*)p; p += (size_t)GG * KK * 2;        //  8.4 MB
    unsigned short* hb    = (unsigned short*)p; p += (size_t)2 * BB * HH * 2;    //  0.5 MB
    unsigned short* gx    = (unsigned short*)p; p += (size_t)LL * BB * GG * 2;   // 134 MB
    unsigned int*   flags = (unsigned int*)p;   p += LL * sizeof(unsigned int);

    hipMemsetAsync(flags, 0, LL * sizeof(unsigned int), stream);
    build_x_kernel<<<dim3(2048), dim3(256), 0, stream>>>(act, inF, xb);
    cast_kernel<<<dim3(1024), dim3(256), 0, stream>>>(Wih, wih_b, GG * KK);
    cast_kernel<<<dim3(64), dim3(256), 0, stream>>>(h0, hb, BB * HH);
    gemm_x_kernel<<<dim3(128, 32), dim3(256), 0, stream>>>(xb, wih_b, gx);

    void* args[] = { (void*)&gx, (void*)&Whh, (void*)&bih, (void*)&bhh,
                     (void*)&c0, (void*)&hb, (void*)&flags, (void*)&out };
    hipLaunchCooperativeKernel((const void*)lstm_kernel, dim3(NBLK), dim3(512), args, 0, stream);
}